// Round 2
// baseline (296.828 us; speedup 1.0000x reference)
//
#include <hip/hip_runtime.h>

// QuantileLoss: scalar = ( sum_rows[ (p0-t0)^2+(p1-t1)^2+(p2-t2)^2 + 2*lower ] ) / (5N)
// lower = p3>p2 ? 1000 : (p3 > 0.95*t2 ? 0 : (p3-0.95*t2)^2)
//
// R1 lesson: direct row-structured loads give 80B/48B lane stride -> ~64 cache
// lines per load instr -> L1 request-rate bound at 17% HBM peak.
// R2: stage 1024-row chunks in LDS with perfectly coalesced float4 loads
// (lane stride 16B), compute from LDS (strides 5/3 floats are odd -> 2-way
// bank aliasing only, which is free on gfx950).

#define NROWS 8388608              // 2^23
#define ROWS_PER_CHUNK 1024
#define NCHUNKS (NROWS / ROWS_PER_CHUNK)   // 8192
#define PCHUNK (ROWS_PER_CHUNK * 5)        // 5120 floats = 20 KB
#define TCHUNK (ROWS_PER_CHUNK * 3)        // 3072 floats = 12 KB

__global__ void __launch_bounds__(256) qloss_partial(
    const float* __restrict__ preds,
    const float* __restrict__ target,
    double* __restrict__ ws)
{
    __shared__ float sp[PCHUNK];
    __shared__ float st[TCHUNK];

    const int t = threadIdx.x;
    double acc = 0.0;

    for (int chunk = blockIdx.x; chunk < NCHUNKS; chunk += gridDim.x) {
        const float4* gp = (const float4*)(preds + (size_t)chunk * PCHUNK);
        const float4* gt = (const float4*)(target + (size_t)chunk * TCHUNK);

        // Coalesced staging: lane stride 16 B, 1 KB per wave-instruction.
        float4 rp[5], rt[3];
        #pragma unroll
        for (int k = 0; k < 5; ++k) rp[k] = gp[t + k * 256];
        #pragma unroll
        for (int k = 0; k < 3; ++k) rt[k] = gt[t + k * 256];
        #pragma unroll
        for (int k = 0; k < 5; ++k) ((float4*)sp)[t + k * 256] = rp[k];
        #pragma unroll
        for (int k = 0; k < 3; ++k) ((float4*)st)[t + k * 256] = rt[k];

        __syncthreads();

        float sum = 0.0f;
        #pragma unroll
        for (int rr = 0; rr < 4; ++rr) {
            const int r = t + rr * 256;          // row within chunk
            const float p0 = sp[5*r + 0];
            const float p1 = sp[5*r + 1];
            const float p2 = sp[5*r + 2];
            const float p3 = sp[5*r + 3];
            const float t0 = st[3*r + 0];
            const float t1 = st[3*r + 1];
            const float t2 = st[3*r + 2];

            const float a0 = p0 - t0;
            const float a1 = p1 - t1;
            const float a2 = p2 - t2;
            const float m  = a0*a0 + a1*a1 + a2*a2;

            const float q = t2 * 0.95f;
            const float d = p3 - q;
            const float lower = (p3 > p2) ? 1000.0f : ((p3 > q) ? 0.0f : d * d);

            sum += m + 2.0f * lower;
        }
        acc += (double)sum;

        __syncthreads();  // protect LDS before next chunk's stores
    }

    // wave64 shuffle reduce
    #pragma unroll
    for (int off = 32; off > 0; off >>= 1)
        acc += __shfl_down(acc, off, 64);

    __shared__ double red[4];
    const int lane = t & 63;
    const int wave = t >> 6;
    if (lane == 0) red[wave] = acc;
    __syncthreads();

    if (t == 0) {
        atomicAdd(ws, red[0] + red[1] + red[2] + red[3]);
    }
}

__global__ void qloss_final(const double* __restrict__ ws, float* __restrict__ out)
{
    *out = (float)(*ws / (5.0 * (double)NROWS));
}

extern "C" void kernel_launch(void* const* d_in, const int* in_sizes, int n_in,
                              void* d_out, int out_size, void* d_ws, size_t ws_size,
                              hipStream_t stream)
{
    const float* preds  = (const float*)d_in[0];
    const float* target = (const float*)d_in[1];
    float* out  = (float*)d_out;
    double* ws  = (double*)d_ws;

    // d_ws is re-poisoned to 0xAA before every timed launch — zero the accumulator.
    hipMemsetAsync(ws, 0, sizeof(double), stream);

    // 2048 blocks; LDS 32 KB/block caps at 5 blocks/CU -> 20 waves/CU.
    qloss_partial<<<2048, 256, 0, stream>>>(preds, target, ws);
    qloss_final<<<1, 1, 0, stream>>>(ws, out);
}